// Round 11
// baseline (6315.896 us; speedup 1.0000x reference)
//
#include <hip/hip_runtime.h>

typedef _Float16 half8 __attribute__((ext_vector_type(8)));
typedef float f32x4 __attribute__((ext_vector_type(4)));
typedef unsigned int u32x4 __attribute__((ext_vector_type(4)));

#define TT 512
#define HH 512
#define P32 0xFFFFFFFFu

// ws layout (bytes):
//   [0,        16777216)  x16  : [32 b][512 t][512 d] f16
//   [16777216, 50331648)  h_pk : [2 dir][512 step][64 j][32 b][8 u] f16 (atomic-poisoned per launch)
//   [50331648, 54525952)  Upk  : packed U frags f16 (2^21)
//   [54525952, 58720256)  Wpk  : packed W frags f16 (2^21)
#define OFF_HPK 16777216
#define OFF_UPK 50331648
#define OFF_WPK 54525952

struct BiasPtrs { const float* b[8]; };

struct PackParams {
  const float* U[8];
  const float* W[8];
  _Float16* Upk;
  _Float16* Wpk;
};

__global__ void convert_x_kernel(const float* __restrict__ x, _Float16* __restrict__ x16) {
  const size_t i = ((size_t)blockIdx.x * blockDim.x + threadIdx.x) * 8;
  float4 v0 = *(const float4*)(x + i);
  float4 v1 = *(const float4*)(x + i + 4);
  half8 h;
  h[0] = (_Float16)v0.x; h[1] = (_Float16)v0.y; h[2] = (_Float16)v0.z; h[3] = (_Float16)v0.w;
  h[4] = (_Float16)v1.x; h[5] = (_Float16)v1.y; h[6] = (_Float16)v1.z; h[7] = (_Float16)v1.w;
  *(half8*)(x16 + i) = h;
}

// Pack U/W into MFMA B-fragment order:
// idx = ((((d*64 + j)*2 + ct)*16 + kt)*64 + l)*8 + jj
// lane l: r15=l&15, kg=l>>4; col -> g=r15&3, u=j*8+ct*4+(r15>>2); k=kt*32+kg*8+jj.
__global__ void pack_frags_kernel(PackParams p) {
  const unsigned n = blockIdx.x * 256 + threadIdx.x;   // 2 * 2^21 total
  const unsigned o = n & 2097151u;
  const int sel = n >> 21;                              // 0 = U, 1 = W
  const int jj = o & 7, l = (o >> 3) & 63, kt = (o >> 9) & 15;
  const int ct = (o >> 13) & 1, j = (o >> 14) & 63, d = (o >> 20) & 1;
  const int r15 = l & 15, kg = l >> 4;
  const int g = r15 & 3;
  const int u = j * 8 + ct * 4 + (r15 >> 2);
  const int k = kt * 32 + kg * 8 + jj;
  const float* M = sel ? p.W[4 * d + g] : p.U[4 * d + g];
  _Float16* dst = sel ? p.Wpk : p.Upk;
  dst[o] = (_Float16)M[k * HH + u];
}

// Poison h_pk with AGENT-ATOMIC stores: goes to the coherence point, never
// leaves poison lines (clean or dirty) in any XCD L2.
__global__ void poison_kernel(unsigned long long* __restrict__ p) {
  const unsigned i = (blockIdx.x * 256 + threadIdx.x) * 4;
#pragma unroll
  for (int k = 0; k < 4; ++k)
    __hip_atomic_store(p + i + k, 0xFFFFFFFFFFFFFFFFull,
                       __ATOMIC_RELAXED, __HIP_MEMORY_SCOPE_AGENT);
}

__device__ __forceinline__ float hsig(float x) {
  return fminf(fmaxf(fmaf(x, 0.2f, 0.5f), 0.0f), 1.0f);
}

__device__ __forceinline__ float fast_tanh(float x) {
  const float e = __expf(2.0f * x);
  return fmaf(-2.0f, __builtin_amdgcn_rcpf(e + 1.0f), 1.0f);
}

// 128 WGs x 256 thr (cooperative). WG = (d = bid>>6, j = bid&63) owns units
// [j*8, j*8+8) x 4 gates = 32 cols. Wave w: rows rt=(w&1)*16, cols ct=(w>>1)*16,
// full K=512. Weights live in LDS (ds_read per use — no L2 reload RTs).
// Sync: NONE. h_pk pre-poisoned via atomic stores; producers fire 8B agent
// stores with no drain/flag; consumers bulk-issue 4B agent-atomic loads
// (bypass L2 — cannot see stale cache), verify per dword (4B cannot tear),
// retry sequentially (self-throttling, <=1 outstanding retry per lane).
__global__ __launch_bounds__(256, 1) void lstm_scan_kernel(
    const _Float16* __restrict__ x16,
    _Float16* __restrict__ h_pk,
    const _Float16* __restrict__ Upk,
    const _Float16* __restrict__ Wpk,
    BiasPtrs bp) {
  const int tid = threadIdx.x;
  const int bid = blockIdx.x;
  const int d   = bid >> 6;
  const int j   = bid & 63;
  const int w   = tid >> 6;
  const int l   = tid & 63;
  const int r15 = l & 15;
  const int kg  = l >> 4;
  const int rt  = w & 1;
  const int ct  = w >> 1;
  const int arow = rt * 16 + r15;

  __shared__ __align__(16) half8 ulds[2 * 16 * 64];   // 32 KB, [ct][kt][l]
  __shared__ __align__(16) half8 wlds[2 * 16 * 64];   // 32 KB
  __shared__ __align__(16) float zlds[32 * 36];
  __shared__ __align__(16) unsigned short hlds[256];

  // Stage this WG's weight fragments into LDS once (waves rt==0 cover both ct sets).
  {
    const half8* ub = (const half8*)Upk;
    const half8* wb = (const half8*)Wpk;
    const int base = (((d * 64 + j) * 2 + ct) * 16) * 64 + l;
    if (rt == 0) {
#pragma unroll
      for (int kt = 0; kt < 16; ++kt) {
        ulds[(ct * 16 + kt) * 64 + l] = ub[base + kt * 64];
        wlds[(ct * 16 + kt) * 64 + l] = wb[base + kt * 64];
      }
    }
  }

  const int b_e  = tid >> 3;
  const int uu_e = tid & 7;
  const int u_e  = j * 8 + uu_e;
  const int slot_e = (uu_e >> 2) * 16 + (uu_e & 3) * 4;
  f32x4 biasv;
#pragma unroll
  for (int g = 0; g < 4; ++g) biasv[g] = bp.b[4 * d + g][u_e];

  __syncthreads();   // weights staged

  float c = 0.0f;

  for (int s = 0; s < TT; ++s) {
    const int t = d ? (TT - 1 - s) : s;
    const unsigned* hbase =
        (const unsigned*)(h_pk + (size_t)(d * TT + (s ? s - 1 : 0)) * 16384);

    // 1) Bulk-issue all 64 h dword atomic loads (64 outstanding, ~1 RT).
    unsigned hs[16][4];
    if (s > 0) {
#pragma unroll
      for (int kt = 0; kt < 16; ++kt) {
        const unsigned* q = hbase + (((kt * 4 + kg) * 32 + arow) << 2);
#pragma unroll
        for (int e = 0; e < 4; ++e)
          hs[kt][e] = __hip_atomic_load(q + e, __ATOMIC_RELAXED, __HIP_MEMORY_SCOPE_AGENT);
      }
    }
    __builtin_amdgcn_sched_barrier(0);

    // 2) x_t fragments (plain cached loads).
    half8 xa[16];
    {
      const half8* xb = (const half8*)(x16 + ((size_t)arow * TT + t) * HH);
#pragma unroll
      for (int kt = 0; kt < 16; ++kt) xa[kt] = xb[kt * 4 + kg];
    }

    // 3) x_t @ W from LDS weights — overlaps the h round trip.
    f32x4 acc0 = {0,0,0,0}, acc1 = {0,0,0,0}, acc2 = {0,0,0,0}, acc3 = {0,0,0,0};
#pragma unroll
    for (int kt = 0; kt < 16; ++kt) {
      const half8 wk = wlds[(ct * 16 + kt) * 64 + l];
      if ((kt & 3) == 0)      acc0 = __builtin_amdgcn_mfma_f32_16x16x32_f16(xa[kt], wk, acc0, 0, 0, 0);
      else if ((kt & 3) == 1) acc1 = __builtin_amdgcn_mfma_f32_16x16x32_f16(xa[kt], wk, acc1, 0, 0, 0);
      else if ((kt & 3) == 2) acc2 = __builtin_amdgcn_mfma_f32_16x16x32_f16(xa[kt], wk, acc2, 0, 0, 0);
      else                    acc3 = __builtin_amdgcn_mfma_f32_16x16x32_f16(xa[kt], wk, acc3, 0, 0, 0);
    }
    __builtin_amdgcn_sched_barrier(0);

    // 4) Verify per dword (4B granule — cannot tear), retry stragglers
    //    sequentially (self-throttled), then h@U from LDS weights.
    if (s > 0) {
#pragma unroll
      for (int kt = 0; kt < 16; ++kt) {
        unsigned v0 = hs[kt][0], v1 = hs[kt][1], v2 = hs[kt][2], v3 = hs[kt][3];
        if (v0 == P32 || v1 == P32 || v2 == P32 || v3 == P32) {
          const unsigned* q = hbase + (((kt * 4 + kg) * 32 + arow) << 2);
          while (v0 == P32) v0 = __hip_atomic_load(q + 0, __ATOMIC_RELAXED, __HIP_MEMORY_SCOPE_AGENT);
          while (v1 == P32) v1 = __hip_atomic_load(q + 1, __ATOMIC_RELAXED, __HIP_MEMORY_SCOPE_AGENT);
          while (v2 == P32) v2 = __hip_atomic_load(q + 2, __ATOMIC_RELAXED, __HIP_MEMORY_SCOPE_AGENT);
          while (v3 == P32) v3 = __hip_atomic_load(q + 3, __ATOMIC_RELAXED, __HIP_MEMORY_SCOPE_AGENT);
        }
        u32x4 u; u[0] = v0; u[1] = v1; u[2] = v2; u[3] = v3;
        const half8 a  = __builtin_bit_cast(half8, u);
        const half8 uk = ulds[(ct * 16 + kt) * 64 + l];
        if ((kt & 3) == 0)      acc0 = __builtin_amdgcn_mfma_f32_16x16x32_f16(a, uk, acc0, 0, 0, 0);
        else if ((kt & 3) == 1) acc1 = __builtin_amdgcn_mfma_f32_16x16x32_f16(a, uk, acc1, 0, 0, 0);
        else if ((kt & 3) == 2) acc2 = __builtin_amdgcn_mfma_f32_16x16x32_f16(a, uk, acc2, 0, 0, 0);
        else                    acc3 = __builtin_amdgcn_mfma_f32_16x16x32_f16(a, uk, acc3, 0, 0, 0);
      }
    }
    const f32x4 z = (acc0 + acc1) + (acc2 + acc3);

    // z -> LDS. D-frag: col = r15, row = kg*4 + i.
#pragma unroll
    for (int i = 0; i < 4; ++i)
      zlds[(rt * 16 + kg * 4 + i) * 36 + ct * 16 + r15] = z[i];
    __syncthreads();

    // Elementwise LSTM cell. |h| < 1 strictly => data dword can never be P32.
    f32x4 pre = *(const f32x4*)&zlds[(size_t)b_e * 36 + slot_e] + biasv;
    const float ig = hsig(pre[0]);
    const float fg = hsig(pre[1]);
    const float gg = fast_tanh(pre[2]);
    const float og = hsig(pre[3]);
    c = fg * c + ig * gg;
    const float h = og * fast_tanh(c);

    hlds[tid] = __builtin_bit_cast(unsigned short, (_Float16)h);
    __syncthreads();

    // 5) Publish: fire-and-forget 8B agent stores. No waitcnt, no flag.
    if (tid < 64) {
      const unsigned long long v = ((const unsigned long long*)hlds)[tid];
      unsigned long long* dst = (unsigned long long*)h_pk +
                                ((size_t)(d * TT + s) * 64 + j) * 64 + tid;
      __hip_atomic_store(dst, v, __ATOMIC_RELAXED, __HIP_MEMORY_SCOPE_AGENT);
    }
  }
}

// out[b][t][u] = h_fwd[t] + h_bwd[t]  (Theano: backward stacked in iteration
// order without re-reversing; scan stored bwd iteration s at slot s).
// Safe plain loads: dispatch acquire invalidates caches; no poison was ever
// cached (all h_pk writers/readers in-scan were agent-atomic).
__global__ void sum_out_kernel(const _Float16* __restrict__ h_pk, float* __restrict__ out) {
  const unsigned idx = blockIdx.x * 256 + threadIdx.x;   // 32*512*64
  const int j = idx & 63;
  const int t = (idx >> 6) & 511;
  const int b = idx >> 15;
  half8 hf = ((const half8*)h_pk)[((size_t)t * 64 + j) * 32 + b];
  half8 hg = ((const half8*)h_pk)[((size_t)(TT + t) * 64 + j) * 32 + b];
  float* o = out + (((size_t)b * TT + t) * HH + j * 8);
  float4 r0, r1;
  r0.x = (float)hf[0] + (float)hg[0]; r0.y = (float)hf[1] + (float)hg[1];
  r0.z = (float)hf[2] + (float)hg[2]; r0.w = (float)hf[3] + (float)hg[3];
  r1.x = (float)hf[4] + (float)hg[4]; r1.y = (float)hf[5] + (float)hg[5];
  r1.z = (float)hf[6] + (float)hg[6]; r1.w = (float)hf[7] + (float)hg[7];
  *(float4*)o = r0;
  *(float4*)(o + 4) = r1;
}

extern "C" void kernel_launch(void* const* d_in, const int* in_sizes, int n_in,
                              void* d_out, int out_size, void* d_ws, size_t ws_size,
                              hipStream_t stream) {
  (void)in_sizes; (void)n_in; (void)out_size; (void)ws_size;
  char* ws = (char*)d_ws;
  _Float16* x16  = (_Float16*)ws;
  _Float16* h_pk = (_Float16*)(ws + OFF_HPK);
  _Float16* Upk  = (_Float16*)(ws + OFF_UPK);
  _Float16* Wpk  = (_Float16*)(ws + OFF_WPK);

  convert_x_kernel<<<4096, 256, 0, stream>>>((const float*)d_in[0], x16);

  PackParams pp;
  for (int g = 0; g < 8; ++g) {
    pp.W[g] = (const float*)d_in[1 + g];
    pp.U[g] = (const float*)d_in[9 + g];
  }
  pp.Upk = Upk; pp.Wpk = Wpk;
  pack_frags_kernel<<<16384, 256, 0, stream>>>(pp);

  // Atomic poison fill: 33554432 B = 4194304 ull = 4096 blocks * 256 thr * 4.
  poison_kernel<<<4096, 256, 0, stream>>>((unsigned long long*)(ws + OFF_HPK));

  BiasPtrs bp;
  for (int g = 0; g < 8; ++g) bp.b[g] = (const float*)d_in[17 + g];

  void* args[] = { (void*)&x16, (void*)&h_pk, (void*)&Upk, (void*)&Wpk, (void*)&bp };
  hipLaunchCooperativeKernel((const void*)lstm_scan_kernel, dim3(128), dim3(256),
                             args, 0, stream);

  sum_out_kernel<<<4096, 256, 0, stream>>>(h_pk, (float*)d_out);
}

// Round 12
// 1773.230 us; speedup vs baseline: 3.5618x; 3.5618x over previous
//
#include <hip/hip_runtime.h>

typedef _Float16 half8 __attribute__((ext_vector_type(8)));
typedef float f32x4 __attribute__((ext_vector_type(4)));

#define TT 512
#define HH 512

// ws layout (bytes):
//   [0,        16777216)  x16   : [32 b][512 t][512 d] f16
//   [16777216, 50331648)  h_pk  : [2 dir][512 step][64 j][32 b][8 u] f16
//   [50331648, 50335744)  flags : [2 dir][8 slot][64 wg] int (epoch ring)
//   [50339840, 54534144)  Upk   : packed U frags f16 (2^21)
//   [54534144, 58728448)  Wpk   : packed W frags f16 (2^21)
#define OFF_HPK   16777216
#define OFF_FLAGS 50331648
#define OFF_UPK   50339840
#define OFF_WPK   54534144

struct BiasPtrs { const float* b[8]; };

struct PackParams {
  const float* U[8];
  const float* W[8];
  _Float16* Upk;
  _Float16* Wpk;
};

__global__ void convert_x_kernel(const float* __restrict__ x, _Float16* __restrict__ x16) {
  const size_t i = ((size_t)blockIdx.x * blockDim.x + threadIdx.x) * 8;
  float4 v0 = *(const float4*)(x + i);
  float4 v1 = *(const float4*)(x + i + 4);
  half8 h;
  h[0] = (_Float16)v0.x; h[1] = (_Float16)v0.y; h[2] = (_Float16)v0.z; h[3] = (_Float16)v0.w;
  h[4] = (_Float16)v1.x; h[5] = (_Float16)v1.y; h[6] = (_Float16)v1.z; h[7] = (_Float16)v1.w;
  *(half8*)(x16 + i) = h;
}

// Pack U/W into MFMA B-fragment order:
// idx = ((((d*64 + j)*2 + ct)*16 + kt)*64 + l)*8 + jj
// lane l: r15=l&15, kg=l>>4; col -> g=r15&3, u=j*8+ct*4+(r15>>2); k=kt*32+kg*8+jj.
__global__ void pack_frags_kernel(PackParams p) {
  const unsigned n = blockIdx.x * 256 + threadIdx.x;   // 2 * 2^21 total
  const unsigned o = n & 2097151u;
  const int sel = n >> 21;                              // 0 = U, 1 = W
  const int jj = o & 7, l = (o >> 3) & 63, kt = (o >> 9) & 15;
  const int ct = (o >> 13) & 1, j = (o >> 14) & 63, d = (o >> 20) & 1;
  const int r15 = l & 15, kg = l >> 4;
  const int g = r15 & 3;
  const int u = j * 8 + ct * 4 + (r15 >> 2);
  const int k = kt * 32 + kg * 8 + jj;
  const float* M = sel ? p.W[4 * d + g] : p.U[4 * d + g];
  _Float16* dst = sel ? p.Wpk : p.Upk;
  dst[o] = (_Float16)M[k * HH + u];
}

// Zero flags with AGENT-ATOMIC stores (no dirty L2 lines over live flags).
__global__ void zero_flags_kernel(int* __restrict__ p) {
  __hip_atomic_store(p + blockIdx.x * 256 + threadIdx.x, 0,
                     __ATOMIC_RELAXED, __HIP_MEMORY_SCOPE_AGENT);
}

__device__ __forceinline__ float hsig(float x) {
  return fminf(fmaxf(fmaf(x, 0.2f, 0.5f), 0.0f), 1.0f);
}

__device__ __forceinline__ float fast_tanh(float x) {
  const float e = __expf(2.0f * x);
  return fmaf(-2.0f, __builtin_amdgcn_rcpf(e + 1.0f), 1.0f);
}

// 128 WGs x 256 thr (cooperative). WG = (d = bid>>6, j = bid&63) owns units
// [j*8, j*8+8) x 4 gates = 32 cols. Wave w: rows rt=(w&1)*16, cols ct=(w>>1)*16,
// full K=512.
// Weights live in LDS (staged once; ds_read ~12cy per use) — eliminates the
// per-step 64KB/WG weight refetch that thrashed XCD L2 and put L3/HBM-class
// legs on the critical path (rounds 3-8: FETCH 263MB, VGPR<=104 proves
// register residency never happened).
// Sync (round-8 proven): parallel per-WG epoch flags (ring 8), 64-lane
// coalesced poll; publish = wave-0 agent-atomic h stores + vmcnt(0) + flag.
// Consume = plain dwordx4 h loads (XCD-L2 dedup preserved).
__global__ __launch_bounds__(256, 1) void lstm_scan_kernel(
    const _Float16* __restrict__ x16,
    _Float16* __restrict__ h_pk,
    int* __restrict__ flags,
    const _Float16* __restrict__ Upk,
    const _Float16* __restrict__ Wpk,
    BiasPtrs bp) {
  const int tid = threadIdx.x;
  const int bid = blockIdx.x;
  const int d   = bid >> 6;
  const int j   = bid & 63;
  const int w   = tid >> 6;
  const int l   = tid & 63;
  const int r15 = l & 15;
  const int kg  = l >> 4;
  const int rt  = w & 1;
  const int ct  = w >> 1;
  const int arow = rt * 16 + r15;

  __shared__ __align__(16) half8 ulds[2 * 16 * 64];   // 32 KB, [ct][kt][l]
  __shared__ __align__(16) half8 wlds[2 * 16 * 64];   // 32 KB
  __shared__ __align__(16) float zlds[32 * 36];
  __shared__ __align__(16) unsigned short hlds[256];

  // Stage this WG's weight fragments into LDS once (rt==0 waves cover both ct).
  {
    const half8* ub = (const half8*)Upk;
    const half8* wb = (const half8*)Wpk;
    const int base = (((d * 64 + j) * 2 + ct) * 16) * 64 + l;
    if (rt == 0) {
#pragma unroll
      for (int kt = 0; kt < 16; ++kt) {
        ulds[(ct * 16 + kt) * 64 + l] = ub[base + kt * 64];
        wlds[(ct * 16 + kt) * 64 + l] = wb[base + kt * 64];
      }
    }
  }

  const int b_e  = tid >> 3;
  const int uu_e = tid & 7;
  const int u_e  = j * 8 + uu_e;
  const int slot_e = (uu_e >> 2) * 16 + (uu_e & 3) * 4;
  f32x4 biasv;
#pragma unroll
  for (int g = 0; g < 4; ++g) biasv[g] = bp.b[4 * d + g][u_e];

  __syncthreads();   // weights staged

  float c = 0.0f;

  for (int s = 0; s < TT; ++s) {
    const int t = d ? (TT - 1 - s) : s;

    // 1) Issue x_t fragment loads (plain; fetch hides under the poll).
    half8 xa[16];
    {
      const half8* xb = (const half8*)(x16 + ((size_t)arow * TT + t) * HH);
#pragma unroll
      for (int kt = 0; kt < 16; ++kt) xa[kt] = xb[kt * 4 + kg];
    }
    __builtin_amdgcn_sched_barrier(0);

    // 2) Poll producer flags (64-lane coalesced; guaranteed by drain+order).
    if (s > 0) {
      if (tid < 64) {
        const int* fl = flags + ((d * 8 + ((s - 1) & 7)) << 6) + tid;
        while (__hip_atomic_load(fl, __ATOMIC_RELAXED, __HIP_MEMORY_SCOPE_AGENT) < s) {
          __builtin_amdgcn_s_sleep(1);
        }
      }
      __syncthreads();
    }
    __builtin_amdgcn_sched_barrier(0);

    // 3) Issue h(s-1) plain dwordx4 loads (XCD-L2 dedup across the 8 same-L2 WGs).
    half8 ha[16];
    if (s > 0) {
      const half8* hb = (const half8*)(h_pk + (size_t)(d * TT + (s - 1)) * 16384);
#pragma unroll
      for (int kt = 0; kt < 16; ++kt) ha[kt] = hb[(kt * 4 + kg) * 32 + arow];
    }
    __builtin_amdgcn_sched_barrier(0);

    // 4) x_t @ W from LDS weights — executes while h loads are in flight.
    f32x4 acc0 = {0,0,0,0}, acc1 = {0,0,0,0}, acc2 = {0,0,0,0}, acc3 = {0,0,0,0};
#pragma unroll
    for (int kt = 0; kt < 16; ++kt) {
      const half8 wk = wlds[(ct * 16 + kt) * 64 + l];
      if ((kt & 3) == 0)      acc0 = __builtin_amdgcn_mfma_f32_16x16x32_f16(xa[kt], wk, acc0, 0, 0, 0);
      else if ((kt & 3) == 1) acc1 = __builtin_amdgcn_mfma_f32_16x16x32_f16(xa[kt], wk, acc1, 0, 0, 0);
      else if ((kt & 3) == 2) acc2 = __builtin_amdgcn_mfma_f32_16x16x32_f16(xa[kt], wk, acc2, 0, 0, 0);
      else                    acc3 = __builtin_amdgcn_mfma_f32_16x16x32_f16(xa[kt], wk, acc3, 0, 0, 0);
    }
    __builtin_amdgcn_sched_barrier(0);

    // 5) h(s-1) @ U from LDS weights.
    if (s > 0) {
#pragma unroll
      for (int kt = 0; kt < 16; ++kt) {
        const half8 uk = ulds[(ct * 16 + kt) * 64 + l];
        if ((kt & 3) == 0)      acc0 = __builtin_amdgcn_mfma_f32_16x16x32_f16(ha[kt], uk, acc0, 0, 0, 0);
        else if ((kt & 3) == 1) acc1 = __builtin_amdgcn_mfma_f32_16x16x32_f16(ha[kt], uk, acc1, 0, 0, 0);
        else if ((kt & 3) == 2) acc2 = __builtin_amdgcn_mfma_f32_16x16x32_f16(ha[kt], uk, acc2, 0, 0, 0);
        else                    acc3 = __builtin_amdgcn_mfma_f32_16x16x32_f16(ha[kt], uk, acc3, 0, 0, 0);
      }
    }
    const f32x4 z = (acc0 + acc1) + (acc2 + acc3);

    // z -> LDS. D-frag: col = r15, row = kg*4 + i.
#pragma unroll
    for (int i = 0; i < 4; ++i)
      zlds[(rt * 16 + kg * 4 + i) * 36 + ct * 16 + r15] = z[i];
    __syncthreads();

    // Elementwise LSTM cell.
    f32x4 pre = *(const f32x4*)&zlds[(size_t)b_e * 36 + slot_e] + biasv;
    const float ig = hsig(pre[0]);
    const float fg = hsig(pre[1]);
    const float gg = fast_tanh(pre[2]);
    const float og = hsig(pre[3]);
    c = fg * c + ig * gg;
    const float h = og * fast_tanh(c);

    hlds[tid] = __builtin_bit_cast(unsigned short, (_Float16)h);
    __syncthreads();

    // 6) Publish: wave 0 stores the WG's contiguous 512 B slice (agent atomic,
    //    IF-visible), drains, then lane 0 sets this WG's epoch flag.
    if (tid < 64) {
      const unsigned long long v = ((const unsigned long long*)hlds)[tid];
      unsigned long long* dst = (unsigned long long*)h_pk +
                                ((size_t)(d * TT + s) * 64 + j) * 64 + tid;
      __hip_atomic_store(dst, v, __ATOMIC_RELAXED, __HIP_MEMORY_SCOPE_AGENT);
      asm volatile("s_waitcnt vmcnt(0)" ::: "memory");
      if (tid == 0)
        __hip_atomic_store(flags + ((d * 8 + (s & 7)) << 6) + j, s + 1,
                           __ATOMIC_RELAXED, __HIP_MEMORY_SCOPE_AGENT);
    }
  }
}

// out[b][t][u] = h_fwd[t] + h_bwd[t]  (Theano: backward stacked in iteration
// order without re-reversing; scan stored bwd iteration s at slot s).
__global__ void sum_out_kernel(const _Float16* __restrict__ h_pk, float* __restrict__ out) {
  const unsigned idx = blockIdx.x * 256 + threadIdx.x;   // 32*512*64
  const int j = idx & 63;
  const int t = (idx >> 6) & 511;
  const int b = idx >> 15;
  half8 hf = ((const half8*)h_pk)[((size_t)t * 64 + j) * 32 + b];
  half8 hg = ((const half8*)h_pk)[((size_t)(TT + t) * 64 + j) * 32 + b];
  float* o = out + (((size_t)b * TT + t) * HH + j * 8);
  float4 r0, r1;
  r0.x = (float)hf[0] + (float)hg[0]; r0.y = (float)hf[1] + (float)hg[1];
  r0.z = (float)hf[2] + (float)hg[2]; r0.w = (float)hf[3] + (float)hg[3];
  r1.x = (float)hf[4] + (float)hg[4]; r1.y = (float)hf[5] + (float)hg[5];
  r1.z = (float)hf[6] + (float)hg[6]; r1.w = (float)hf[7] + (float)hg[7];
  *(float4*)o = r0;
  *(float4*)(o + 4) = r1;
}

extern "C" void kernel_launch(void* const* d_in, const int* in_sizes, int n_in,
                              void* d_out, int out_size, void* d_ws, size_t ws_size,
                              hipStream_t stream) {
  (void)in_sizes; (void)n_in; (void)out_size; (void)ws_size;
  char* ws = (char*)d_ws;
  _Float16* x16   = (_Float16*)ws;
  _Float16* h_pk  = (_Float16*)(ws + OFF_HPK);
  int*      flags = (int*)(ws + OFF_FLAGS);
  _Float16* Upk   = (_Float16*)(ws + OFF_UPK);
  _Float16* Wpk   = (_Float16*)(ws + OFF_WPK);

  convert_x_kernel<<<4096, 256, 0, stream>>>((const float*)d_in[0], x16);

  PackParams pp;
  for (int g = 0; g < 8; ++g) {
    pp.W[g] = (const float*)d_in[1 + g];
    pp.U[g] = (const float*)d_in[9 + g];
  }
  pp.Upk = Upk; pp.Wpk = Wpk;
  pack_frags_kernel<<<16384, 256, 0, stream>>>(pp);

  zero_flags_kernel<<<4, 256, 0, stream>>>(flags);   // 1024 ints, atomic stores

  BiasPtrs bp;
  for (int g = 0; g < 8; ++g) bp.b[g] = (const float*)d_in[17 + g];

  void* args[] = { (void*)&x16, (void*)&h_pk, (void*)&flags,
                   (void*)&Upk, (void*)&Wpk, (void*)&bp };
  hipLaunchCooperativeKernel((const void*)lstm_scan_kernel, dim3(128), dim3(256),
                             args, 0, stream);

  sum_out_kernel<<<4096, 256, 0, stream>>>(h_pk, (float*)d_out);
}